// Round 4
// baseline (17.723 us; speedup 1.0000x reference)
//
#include <hip/hip_runtime.h>

// y[i,o,n] = sum_{j,k} x[j,(o-1)%56, n+k-1]*W[i,j,0,k]
//          + sum_{j,k} x[j,(o-2)%56, n+k-1]*W[i,j,1,k]
// x: (1,64,56,56) f32, W: (64,64,2,3) f32 [i,j,l,k], y: (1,64,56,56) f32
//
// Block = (o-pair, 4-i group), 512 threads (8 waves), j split 8 ways.
// o and o+1 share row (o-1): 3 x-rows feed 48 FMAs per j-iter.

#define O_DIM 56
#define N_DIM 56
#define J_DIM 64
#define I_DIM 64

__global__ __launch_bounds__(512) void conv_shift_kernel(
    const float* __restrict__ x, const float* __restrict__ w, float* __restrict__ y)
{
    const int op   = blockIdx.x;        // 0..27 -> o0 = 2*op, o1 = o0+1
    const int ig   = blockIdx.y;        // 0..15 -> i in [ig*4, ig*4+4)
    const int tid  = threadIdx.x;       // 0..511
    const int wave = tid >> 6;          // 0..7  -> j in [wave*8, wave*8+8)
    const int n    = tid & 63;          // lane; active n < 56
    const int nc   = (n < N_DIM) ? n : (N_DIM - 1);
    const bool hasL = (nc > 0);
    const bool hasR = (nc < N_DIM - 1);

    const int o0 = op * 2;
    const int rowP = (o0 + O_DIM - 1) % O_DIM;   // o0-1 (shared)
    const int rowQ = (o0 + O_DIM - 2) % O_DIM;   // o0-2
    const int rowR = o0;                          // o0

    const int i0 = ig * 4;
    const int j0 = wave * 8;

    float acc[2][4] = {{0.f,0.f,0.f,0.f},{0.f,0.f,0.f,0.f}};

    #pragma unroll
    for (int jj = 0; jj < 8; ++jj) {
        const int j = j0 + jj;
        const float* base = x + j * (O_DIM * N_DIM);
        const float* pP = base + rowP * N_DIM;
        const float* pQ = base + rowQ * N_DIM;
        const float* pR = base + rowR * N_DIM;

        const float cP = pP[nc], cQ = pQ[nc], cR = pR[nc];
        const float lP = hasL ? pP[nc - 1] : 0.f;
        const float lQ = hasL ? pQ[nc - 1] : 0.f;
        const float lR = hasL ? pR[nc - 1] : 0.f;
        const float rP = hasR ? pP[nc + 1] : 0.f;
        const float rQ = hasR ? pQ[nc + 1] : 0.f;
        const float rR = hasR ? pR[nc + 1] : 0.f;

        #pragma unroll
        for (int q = 0; q < 4; ++q) {
            const float* wq = w + ((i0 + q) * J_DIM + j) * 6;  // wave-uniform -> s_load
            const float w00 = wq[0], w01 = wq[1], w02 = wq[2];
            const float w10 = wq[3], w11 = wq[4], w12 = wq[5];
            // o0: l=0 row = rowP, l=1 row = rowQ
            acc[0][q] += lP * w00 + cP * w01 + rP * w02
                       + lQ * w10 + cQ * w11 + rQ * w12;
            // o1: l=0 row = rowR, l=1 row = rowP
            acc[1][q] += lR * w00 + cR * w01 + rR * w02
                       + lP * w10 + cP * w11 + rP * w12;
        }
    }

    // Cross-wave reduction over the 8-way j-split: red[wave][(o,i) slot][n]
    __shared__ float red[8][8][64];
    #pragma unroll
    for (int q = 0; q < 4; ++q) {
        red[wave][q][n]     = acc[0][q];
        red[wave][4 + q][n] = acc[1][q];
    }
    __syncthreads();

    // 448 outputs (2 o x 4 i x 56 n); 512 threads -> at most 1 each
    if (tid < 8 * N_DIM) {
        const int il = tid / N_DIM;          // 0..7
        const int nn = tid % N_DIM;
        const int oo = o0 + (il >> 2);
        const int ii = i0 + (il & 3);
        float v = 0.f;
        #pragma unroll
        for (int wv = 0; wv < 8; ++wv) v += red[wv][il][nn];
        y[(ii * O_DIM + oo) * N_DIM + nn] = v;
    }
}

extern "C" void kernel_launch(void* const* d_in, const int* in_sizes, int n_in,
                              void* d_out, int out_size, void* d_ws, size_t ws_size,
                              hipStream_t stream) {
    const float* x = (const float*)d_in[0];
    const float* w = (const float*)d_in[1];
    float* y = (float*)d_out;

    dim3 grid(O_DIM / 2, I_DIM / 4);  // 28 x 16 = 448 blocks, 8 waves each
    conv_shift_kernel<<<grid, 512, 0, stream>>>(x, w, y);
}

// Round 5
// 13.508 us; speedup vs baseline: 1.3120x; 1.3120x over previous
//
#include <hip/hip_runtime.h>

// y[i,o,n] = sum_{j,k} x[j,(o-1)%56, n+k-1]*W[i,j,0,k]
//          + sum_{j,k} x[j,(o-2)%56, n+k-1]*W[i,j,1,k]
// x: (1,64,56,56) f32, W: (64,64,2,3) f32 [i,j,l,k], y: (1,64,56,56) f32
//
// Block = (o-quad, 4-i group), 512 threads (8 waves), j split 8 ways.
// 4 consecutive o's need only 5 x-rows (o0-2..o0+2): 15 loads -> 96 FMAs/j-iter.

#define O_DIM 56
#define N_DIM 56
#define J_DIM 64
#define I_DIM 64

__global__ __launch_bounds__(512) void conv_shift_kernel(
    const float* __restrict__ x, const float* __restrict__ w, float* __restrict__ y)
{
    const int op   = blockIdx.x;        // 0..13 -> o0 = 4*op
    const int ig   = blockIdx.y;        // 0..15 -> i in [ig*4, ig*4+4)
    const int tid  = threadIdx.x;       // 0..511
    const int wave = tid >> 6;          // 0..7  -> j in [wave*8, wave*8+8)
    const int n    = tid & 63;          // lane; active n < 56
    const int nc   = (n < N_DIM) ? n : (N_DIM - 1);
    const bool hasL = (nc > 0);
    const bool hasR = (nc < N_DIM - 1);

    const int o0 = op * 4;              // 0,4,...,52
    // 5 distinct source rows: e=0..4 -> row (o0-2+e) mod 56.
    // Output o0+d uses row e=d+1 (l=0) and row e=d (l=1).
    int rowIdx[5];
    rowIdx[0] = (o0 + O_DIM - 2) % O_DIM;
    rowIdx[1] = (o0 + O_DIM - 1) % O_DIM;
    rowIdx[2] = o0;
    rowIdx[3] = o0 + 1;                 // o0 <= 52 -> <= 53, no wrap
    rowIdx[4] = o0 + 2;                 //           <= 54, no wrap

    const int i0 = ig * 4;
    const int j0 = wave * 8;

    float acc[4][4];                    // [d (o offset)][q (i offset)]
    #pragma unroll
    for (int d = 0; d < 4; ++d)
        #pragma unroll
        for (int q = 0; q < 4; ++q) acc[d][q] = 0.f;

    #pragma unroll 4
    for (int jj = 0; jj < 8; ++jj) {
        const int j = j0 + jj;
        const float* base = x + j * (O_DIM * N_DIM);

        float Lv[5], Cv[5], Rv[5];
        #pragma unroll
        for (int e = 0; e < 5; ++e) {
            const float* pr = base + rowIdx[e] * N_DIM;
            Cv[e] = pr[nc];
            Lv[e] = hasL ? pr[nc - 1] : 0.f;
            Rv[e] = hasR ? pr[nc + 1] : 0.f;
        }

        #pragma unroll
        for (int q = 0; q < 4; ++q) {
            const float* wq = w + ((i0 + q) * J_DIM + j) * 6;  // wave-uniform -> s_load
            const float w00 = wq[0], w01 = wq[1], w02 = wq[2];
            const float w10 = wq[3], w11 = wq[4], w12 = wq[5];
            #pragma unroll
            for (int d = 0; d < 4; ++d) {
                acc[d][q] += Lv[d + 1] * w00 + Cv[d + 1] * w01 + Rv[d + 1] * w02
                           + Lv[d]     * w10 + Cv[d]     * w11 + Rv[d]     * w12;
            }
        }
    }

    // Cross-wave reduction over the 8-way j-split: red[wave][(d,q) slot][n]
    __shared__ float red[8][16][64];
    #pragma unroll
    for (int d = 0; d < 4; ++d)
        #pragma unroll
        for (int q = 0; q < 4; ++q)
            red[wave][d * 4 + q][n] = acc[d][q];
    __syncthreads();

    // 896 outputs (4 o x 4 i x 56 n); 512 threads -> up to 2 each
    for (int t = tid; t < 16 * N_DIM; t += 512) {
        const int il = t / N_DIM;       // 0..15
        const int nn = t % N_DIM;
        const int oo = o0 + (il >> 2);
        const int ii = i0 + (il & 3);
        float v = 0.f;
        #pragma unroll
        for (int wv = 0; wv < 8; ++wv) v += red[wv][il][nn];
        y[(ii * O_DIM + oo) * N_DIM + nn] = v;
    }
}

extern "C" void kernel_launch(void* const* d_in, const int* in_sizes, int n_in,
                              void* d_out, int out_size, void* d_ws, size_t ws_size,
                              hipStream_t stream) {
    const float* x = (const float*)d_in[0];
    const float* w = (const float*)d_in[1];
    float* y = (float*)d_out;

    dim3 grid(O_DIM / 4, I_DIM / 4);  // 14 x 16 = 224 blocks, 8 waves each
    conv_shift_kernel<<<grid, 512, 0, stream>>>(x, w, y);
}